// Round 3
// baseline (1344.613 us; speedup 1.0000x reference)
//
#include <hip/hip_runtime.h>
#include <math.h>

// ---------------- helpers ----------------
__device__ __forceinline__ void ld16(const float* __restrict__ p, float* a) {
    const float4* q = (const float4*)p;
    float4 v0 = q[0], v1 = q[1], v2 = q[2], v3 = q[3];
    a[0]=v0.x; a[1]=v0.y; a[2]=v0.z; a[3]=v0.w;
    a[4]=v1.x; a[5]=v1.y; a[6]=v1.z; a[7]=v1.w;
    a[8]=v2.x; a[9]=v2.y; a[10]=v2.z; a[11]=v2.w;
    a[12]=v3.x; a[13]=v3.y; a[14]=v3.z; a[15]=v3.w;
}

// ---------------- CSR build (generic: key = ei[keyOfs + e]) ----------------
__global__ __launch_bounds__(256) void k_count(const int* __restrict__ ei, int* __restrict__ cnt,
                                               int E, int keyOfs) {
    int e = blockIdx.x * blockDim.x + threadIdx.x;
    if (e < E) atomicAdd(&cnt[ei[keyOfs + e]], 1);
}

__global__ __launch_bounds__(256) void k_scanA(const int* __restrict__ cnt, int* __restrict__ offs,
                                               int* __restrict__ bsum, int N) {
    __shared__ int s[256];
    int i = blockIdx.x * 256 + threadIdx.x;
    int v = (i < N) ? cnt[i] : 0;
    s[threadIdx.x] = v;
    __syncthreads();
    #pragma unroll
    for (int d = 1; d < 256; d <<= 1) {
        int t = (threadIdx.x >= d) ? s[threadIdx.x - d] : 0;
        __syncthreads();
        s[threadIdx.x] += t;
        __syncthreads();
    }
    if (i < N) offs[i] = s[threadIdx.x] - v;
    if (threadIdx.x == 255) bsum[blockIdx.x] = s[255];
}

__global__ __launch_bounds__(256) void k_scanB(int* __restrict__ bsum, int nb) {
    __shared__ int s[256];
    int v = (threadIdx.x < nb) ? bsum[threadIdx.x] : 0;
    s[threadIdx.x] = v;
    __syncthreads();
    #pragma unroll
    for (int d = 1; d < 256; d <<= 1) {
        int t = (threadIdx.x >= d) ? s[threadIdx.x - d] : 0;
        __syncthreads();
        s[threadIdx.x] += t;
        __syncthreads();
    }
    if (threadIdx.x < nb) bsum[threadIdx.x] = s[threadIdx.x] - v;
}

__global__ __launch_bounds__(256) void k_scanC(int* __restrict__ offs, const int* __restrict__ bsum, int N) {
    int i = blockIdx.x * 256 + threadIdx.x;
    if (i < N) offs[i] += bsum[blockIdx.x];
}

// dst variant: slotOf[e] = slot ; src variant: perm[slot] = e
__global__ __launch_bounds__(256) void k_fillD(const int* __restrict__ ei, const int* __restrict__ offs,
                                               int* __restrict__ cursor, int* __restrict__ slotOf, int E) {
    int e = blockIdx.x * blockDim.x + threadIdx.x;
    if (e < E) {
        int d = ei[E + e];
        slotOf[e] = offs[d] + atomicAdd(&cursor[d], 1);
    }
}
__global__ __launch_bounds__(256) void k_fillS(const int* __restrict__ ei, const int* __restrict__ offs,
                                               int* __restrict__ cursor, int* __restrict__ perm, int E) {
    int e = blockIdx.x * blockDim.x + threadIdx.x;
    if (e < E) {
        int s = ei[e];
        perm[offs[s] + atomicAdd(&cursor[s], 1)] = e;
    }
}

// ---------------- factorized conv: U[n][k][o] + HB[n][o] (row stride 272) ----------------
__global__ __launch_bounds__(256) void k_u(
    const float* __restrict__ h, const float* __restrict__ w2,
    float* __restrict__ U, int N)
{
    int t = blockIdx.x * blockDim.x + threadIdx.x;
    int n = t >> 4, k = t & 15;
    if (n >= N) return;
    float hn[16]; ld16(h + (size_t)n * 16, hn);
    float acc[16];
    #pragma unroll
    for (int o = 0; o < 16; o++) acc[o] = 0.f;
    #pragma unroll
    for (int i = 0; i < 16; i++) {
        const float4* w = (const float4*)(w2 + k * 256 + i * 16);
        float hi = hn[i];
        #pragma unroll
        for (int q = 0; q < 4; q++) {
            float4 wv = w[q];
            acc[q*4+0] += hi * wv.x; acc[q*4+1] += hi * wv.y;
            acc[q*4+2] += hi * wv.z; acc[q*4+3] += hi * wv.w;
        }
    }
    float4* up = (float4*)(U + (size_t)n * 272 + k * 16);
    up[0] = make_float4(acc[0], acc[1], acc[2], acc[3]);
    up[1] = make_float4(acc[4], acc[5], acc[6], acc[7]);
    up[2] = make_float4(acc[8], acc[9], acc[10], acc[11]);
    up[3] = make_float4(acc[12], acc[13], acc[14], acc[15]);
}

__global__ __launch_bounds__(256) void k_hb(
    const float* __restrict__ h, const float* __restrict__ b2,
    float* __restrict__ U, int N)
{
    int t = blockIdx.x * blockDim.x + threadIdx.x;
    int n = t >> 4, o = t & 15;
    if (n >= N) return;
    float acc = 0.f;
    #pragma unroll
    for (int i = 0; i < 16; i++) acc += h[(size_t)n * 16 + i] * b2[i * 16 + o];
    U[(size_t)n * 272 + 256 + o] = acc;
}

// edge kernel over src-sorted order: 400 FMA/edge, U row L1-resident
__global__ __launch_bounds__(256) void k_conv2(
    const int* __restrict__ ei, const float* __restrict__ ea,
    const float* __restrict__ w1, const float* __restrict__ b1,
    const float* __restrict__ U, const int* __restrict__ permS,
    const int* __restrict__ slotOf, float* __restrict__ msg, int E)
{
    int j = blockIdx.x * blockDim.x + threadIdx.x;
    if (j >= E) return;
    int e = permS[j];
    int s = ei[e];

    float a[16];
    #pragma unroll
    for (int k = 0; k < 16; k++) a[k] = b1[k];
    {
        const float4* p = (const float4*)(ea + (size_t)e * 8);
        float4 v0 = p[0], v1 = p[1];
        float eav[8] = {v0.x, v0.y, v0.z, v0.w, v1.x, v1.y, v1.z, v1.w};
        #pragma unroll
        for (int q = 0; q < 8; q++) {
            float ev = eav[q];
            #pragma unroll
            for (int k = 0; k < 16; k++) a[k] += ev * w1[q * 16 + k];
        }
    }
    #pragma unroll
    for (int k = 0; k < 16; k++) a[k] = fmaxf(a[k], 0.f);

    const float* row = U + (size_t)s * 272;
    float m[16];
    {
        const float4* hb = (const float4*)(row + 256);
        float4 h0 = hb[0], h1 = hb[1], h2v = hb[2], h3 = hb[3];
        m[0]=h0.x; m[1]=h0.y; m[2]=h0.z; m[3]=h0.w;
        m[4]=h1.x; m[5]=h1.y; m[6]=h1.z; m[7]=h1.w;
        m[8]=h2v.x; m[9]=h2v.y; m[10]=h2v.z; m[11]=h2v.w;
        m[12]=h3.x; m[13]=h3.y; m[14]=h3.z; m[15]=h3.w;
    }
    #pragma unroll
    for (int k = 0; k < 16; k++) {
        float ak = a[k];
        const float4* w = (const float4*)(row + k * 16);
        #pragma unroll
        for (int q = 0; q < 4; q++) {
            float4 wv = w[q];
            m[q*4+0] += ak * wv.x; m[q*4+1] += ak * wv.y;
            m[q*4+2] += ak * wv.z; m[q*4+3] += ak * wv.w;
        }
    }
    int sl = slotOf[e];
    float4* p = (float4*)(msg + (size_t)sl * 16);
    p[0] = make_float4(m[0], m[1], m[2], m[3]);
    p[1] = make_float4(m[4], m[5], m[6], m[7]);
    p[2] = make_float4(m[8], m[9], m[10], m[11]);
    p[3] = make_float4(m[12], m[13], m[14], m[15]);
}

// ---------------- legacy conv (fallback if ws too small) ----------------
__global__ __launch_bounds__(256) void k_conv(
    const float* __restrict__ h, const int* __restrict__ ei,
    const float* __restrict__ ea,
    const float* __restrict__ w1, const float* __restrict__ b1,
    const float* __restrict__ w2, const float* __restrict__ b2,
    const int* __restrict__ slotOf, float* __restrict__ msg, int E)
{
    int t = blockIdx.x * blockDim.x + threadIdx.x;
    int e0 = t * 2;
    if (e0 >= E) return;
    int e1 = e0 + 1;
    int s0 = ei[e0], s1 = ei[e1];
    float ea0[8], ea1[8];
    {
        const float4* p = (const float4*)(ea + (size_t)e0 * 8);
        float4 v0 = p[0], v1 = p[1];
        ea0[0]=v0.x; ea0[1]=v0.y; ea0[2]=v0.z; ea0[3]=v0.w;
        ea0[4]=v1.x; ea0[5]=v1.y; ea0[6]=v1.z; ea0[7]=v1.w;
        const float4* q = (const float4*)(ea + (size_t)e1 * 8);
        float4 u0 = q[0], u1 = q[1];
        ea1[0]=u0.x; ea1[1]=u0.y; ea1[2]=u0.z; ea1[3]=u0.w;
        ea1[4]=u1.x; ea1[5]=u1.y; ea1[6]=u1.z; ea1[7]=u1.w;
    }
    float h0[16], h1[16];
    ld16(h + (size_t)s0 * 16, h0);
    ld16(h + (size_t)s1 * 16, h1);
    float m0[16], m1[16];
    #pragma unroll
    for (int q = 0; q < 16; q++) { m0[q] = 0.f; m1[q] = 0.f; }
    #pragma unroll 1
    for (int k = 0; k < 16; k++) {
        float bk = b1[k];
        float a0 = bk, a1 = bk;
        #pragma unroll
        for (int j = 0; j < 8; j++) {
            float w = w1[j * 16 + k];
            a0 += ea0[j] * w;
            a1 += ea1[j] * w;
        }
        a0 = fmaxf(a0, 0.f);
        a1 = fmaxf(a1, 0.f);
        const float4* w4 = (const float4*)(w2 + k * 256);
        #pragma unroll
        for (int i = 0; i < 16; i++) {
            float s0v = a0 * h0[i];
            float s1v = a1 * h1[i];
            #pragma unroll
            for (int q = 0; q < 4; q++) {
                float4 w = w4[i * 4 + q];
                m0[q*4+0] += s0v * w.x; m0[q*4+1] += s0v * w.y;
                m0[q*4+2] += s0v * w.z; m0[q*4+3] += s0v * w.w;
                m1[q*4+0] += s1v * w.x; m1[q*4+1] += s1v * w.y;
                m1[q*4+2] += s1v * w.z; m1[q*4+3] += s1v * w.w;
            }
        }
    }
    {
        const float4* b4 = (const float4*)b2;
        #pragma unroll
        for (int i = 0; i < 16; i++) {
            float s0v = h0[i];
            float s1v = h1[i];
            #pragma unroll
            for (int q = 0; q < 4; q++) {
                float4 w = b4[i * 4 + q];
                m0[q*4+0] += s0v * w.x; m0[q*4+1] += s0v * w.y;
                m0[q*4+2] += s0v * w.z; m0[q*4+3] += s0v * w.w;
                m1[q*4+0] += s1v * w.x; m1[q*4+1] += s1v * w.y;
                m1[q*4+2] += s1v * w.z; m1[q*4+3] += s1v * w.w;
            }
        }
    }
    int sl0 = slotOf[e0], sl1 = slotOf[e1];
    float4* p0 = (float4*)(msg + (size_t)sl0 * 16);
    p0[0] = make_float4(m0[0], m0[1], m0[2], m0[3]);
    p0[1] = make_float4(m0[4], m0[5], m0[6], m0[7]);
    p0[2] = make_float4(m0[8], m0[9], m0[10], m0[11]);
    p0[3] = make_float4(m0[12], m0[13], m0[14], m0[15]);
    float4* p1 = (float4*)(msg + (size_t)sl1 * 16);
    p1[0] = make_float4(m1[0], m1[1], m1[2], m1[3]);
    p1[1] = make_float4(m1[4], m1[5], m1[6], m1[7]);
    p1[2] = make_float4(m1[8], m1[9], m1[10], m1[11]);
    p1[3] = make_float4(m1[12], m1[13], m1[14], m1[15]);
}

// ---------------- node update ----------------
__global__ __launch_bounds__(256) void k_node(
    const float* __restrict__ h, const float* __restrict__ msg,
    const int* __restrict__ offs, const int* __restrict__ cnt,
    const float* __restrict__ root, const float* __restrict__ cb,
    float* __restrict__ h2, float* __restrict__ stats, int N)
{
    int t = blockIdx.x * blockDim.x + threadIdx.x;
    int n = t >> 4;
    int o = t & 15;
    float v = 0.f;
    if (n < N) {
        v = cb[o];
        int start = offs[n], deg = cnt[n];
        for (int j = 0; j < deg; j++)
            v += msg[(size_t)(start + j) * 16 + o];
        float hr[16];
        ld16(h + (size_t)n * 16, hr);
        #pragma unroll
        for (int i = 0; i < 16; i++) v += hr[i] * root[i * 16 + o];
        v = fmaxf(v, 0.f);
        h2[(size_t)n * 16 + o] = v;
    }
    __shared__ float ls[256];
    __shared__ float ls2[256];
    int tid = threadIdx.x;
    ls[tid] = v;
    ls2[tid] = v * v;
    __syncthreads();
    #pragma unroll
    for (int s = 128; s >= 16; s >>= 1) {
        if (tid < s) { ls[tid] += ls[tid + s]; ls2[tid] += ls2[tid + s]; }
        __syncthreads();
    }
    if (tid < 16) {
        atomicAdd(&stats[tid], ls[tid]);
        atomicAdd(&stats[16 + tid], ls2[tid]);
    }
}

// ---------------- BN apply ----------------
__global__ __launch_bounds__(256) void k_bn(
    const float* __restrict__ h2, const float* __restrict__ stats,
    const float* __restrict__ g, const float* __restrict__ be,
    float* __restrict__ hout, int N, float invN)
{
    int t = blockIdx.x * blockDim.x + threadIdx.x;
    if (t >= N * 16) return;
    int o = t & 15;
    float m = stats[o] * invN;
    float var = stats[16 + o] * invN - m * m;
    float sc = g[o] * rsqrtf(var + 1e-5f);
    hout[t] = (h2[t] - m) * sc + be[o];
}

// ---------------- mu / logvar / reparameterize ----------------
__global__ __launch_bounds__(256) void k_z(
    const float* __restrict__ h, const float* __restrict__ mu_w, const float* __restrict__ mu_b,
    const float* __restrict__ lv_w, const float* __restrict__ lv_b,
    const float* __restrict__ eps, float* __restrict__ z, int N)
{
    int t = blockIdx.x * blockDim.x + threadIdx.x;
    if (t >= N * 16) return;
    int n = t >> 4;
    int o = t & 15;
    float hr[16];
    ld16(h + (size_t)n * 16, hr);
    float mu = mu_b[o];
    float lv = lv_b[o];
    #pragma unroll
    for (int i = 0; i < 16; i++) {
        mu += hr[i] * mu_w[i * 16 + o];
        lv += hr[i] * lv_w[i * 16 + o];
    }
    lv = fminf(lv, 10.f);
    z[t] = mu + eps[t] * expf(0.5f * lv);
}

// ---------------- decoder: register accumulators, wave-split outputs ----------------
__device__ __forceinline__ void dec64(const float* __restrict__ wmat,
                                      const float* __restrict__ bias,
                                      float* row, int Wof, float* acc)
{
    #pragma unroll
    for (int o = 0; o < 32; o++) acc[o] = bias[Wof + o];
    #pragma unroll 2
    for (int i = 0; i < 64; i++) {
        float ai = row[i];
        const float4* w = (const float4*)(wmat + i * 64 + Wof);
        #pragma unroll
        for (int q = 0; q < 8; q++) {
            float4 wv = w[q];
            acc[q*4+0] += ai * wv.x; acc[q*4+1] += ai * wv.y;
            acc[q*4+2] += ai * wv.z; acc[q*4+3] += ai * wv.w;
        }
    }
    __syncthreads();
    #pragma unroll
    for (int o = 0; o < 32; o++) row[Wof + o] = fmaxf(acc[o], 0.f);
    __syncthreads();
}

__global__ __launch_bounds__(128) void k_dec(
    const float* __restrict__ z, const int* __restrict__ ei,
    const float* __restrict__ dw0, const float* __restrict__ db0,
    const float* __restrict__ dw1, const float* __restrict__ db1,
    const float* __restrict__ dw2, const float* __restrict__ db2,
    const float* __restrict__ dw3, const float* __restrict__ db3,
    const float* __restrict__ dw4, const float* __restrict__ db4,
    float* __restrict__ out, int E)
{
    __shared__ float act[64 * 65];
    int l = threadIdx.x & 63;
    int W = __builtin_amdgcn_readfirstlane(threadIdx.x >> 6);
    int e = blockIdx.x * 64 + l;
    float* row = act + l * 65;

    // stage inputs: wave0 -> z[src] into [0..15], wave1 -> z[dst] into [16..31]
    if (e < E) {
        int nd = (W == 0) ? ei[e] : ei[E + e];
        const float4* zp = (const float4*)(z + (size_t)nd * 16);
        #pragma unroll
        for (int q = 0; q < 4; q++) {
            float4 v = zp[q];
            row[W * 16 + q * 4 + 0] = v.x;
            row[W * 16 + q * 4 + 1] = v.y;
            row[W * 16 + q * 4 + 2] = v.z;
            row[W * 16 + q * 4 + 3] = v.w;
        }
    }
    __syncthreads();

    float acc[32];
    int Wof = W * 32;

    // layer 0: 32 -> 64
    #pragma unroll
    for (int o = 0; o < 32; o++) acc[o] = db0[Wof + o];
    #pragma unroll 2
    for (int i = 0; i < 32; i++) {
        float ai = row[i];
        const float4* w = (const float4*)(dw0 + i * 64 + Wof);
        #pragma unroll
        for (int q = 0; q < 8; q++) {
            float4 wv = w[q];
            acc[q*4+0] += ai * wv.x; acc[q*4+1] += ai * wv.y;
            acc[q*4+2] += ai * wv.z; acc[q*4+3] += ai * wv.w;
        }
    }
    __syncthreads();
    #pragma unroll
    for (int o = 0; o < 32; o++) row[Wof + o] = fmaxf(acc[o], 0.f);
    __syncthreads();

    dec64(dw1, db1, row, Wof, acc);
    dec64(dw2, db2, row, Wof, acc);
    dec64(dw3, db3, row, Wof, acc);

    // final: 64 -> 8 ; wave W computes outputs [W*4, W*4+4)
    float r[4];
    #pragma unroll
    for (int j = 0; j < 4; j++) r[j] = db4[W * 4 + j];
    #pragma unroll 2
    for (int i = 0; i < 64; i++) {
        float ai = row[i];
        float4 wv = *(const float4*)(dw4 + i * 8 + W * 4);
        r[0] += ai * wv.x; r[1] += ai * wv.y; r[2] += ai * wv.z; r[3] += ai * wv.w;
    }
    if (e < E) {
        *(float4*)(out + (size_t)e * 8 + W * 4) = make_float4(r[0], r[1], r[2], r[3]);
    }
}

// ---------------- launch ----------------
extern "C" void kernel_launch(void* const* d_in, const int* in_sizes, int n_in,
                              void* d_out, int out_size, void* d_ws, size_t ws_size,
                              hipStream_t stream)
{
    const float* x   = (const float*)d_in[0];
    const int*   ei  = (const int*)d_in[1];
    const float* ea  = (const float*)d_in[2];
    const float* eps = (const float*)d_in[3];
    const float* w1  = (const float*)d_in[4];
    const float* b1  = (const float*)d_in[5];
    const float* w2  = (const float*)d_in[6];
    const float* b2  = (const float*)d_in[7];
    const float* root[4]; const float* cb[4]; const float* g[4]; const float* be[4];
    for (int l = 0; l < 4; l++) {
        root[l] = (const float*)d_in[8 + 4*l];
        cb[l]   = (const float*)d_in[9 + 4*l];
        g[l]    = (const float*)d_in[10 + 4*l];
        be[l]   = (const float*)d_in[11 + 4*l];
    }
    const float* mu_w = (const float*)d_in[24];
    const float* mu_b = (const float*)d_in[25];
    const float* lv_w = (const float*)d_in[26];
    const float* lv_b = (const float*)d_in[27];
    const float* dw[5]; const float* db[5];
    for (int i = 0; i < 5; i++) {
        dw[i] = (const float*)d_in[28 + 2*i];
        db[i] = (const float*)d_in[29 + 2*i];
    }
    float* out = (float*)d_out;

    int N = in_sizes[0] / 16;
    int E = in_sizes[2] / 8;

    // ---- workspace layout ----
    int*   cnt    = (int*)d_ws;                  // N
    int*   cursor = cnt + N;                     // N
    int*   offs   = cursor + N;                  // N
    int*   bsum   = offs + N;                    // 256
    int*   slotOf = bsum + 256;                  // E
    float* stats  = (float*)(slotOf + E);        // 64
    float* msg    = stats + 64;                  // E*16
    float* hbuf   = msg + (size_t)E * 16;        // N*16
    float* h2     = hbuf + (size_t)N * 16;       // N*16
    float* zbuf   = h2 + (size_t)N * 16;         // N*16
    // factorized-path extras
    int*   cntS   = (int*)(zbuf + (size_t)N * 16); // N
    int*   cursorS= cntS + N;                    // N
    int*   offsS  = cursorS + N;                 // N
    int*   bsumS  = offsS + N;                   // 256
    int*   permS  = bsumS + 256;                 // E
    float* U      = (float*)(permS + E);         // N*272
    size_t needed = (size_t)((char*)(U + (size_t)N * 272) - (char*)d_ws);
    bool fact = (ws_size >= needed);

    int nbScan = (N + 255) / 256;                // 196 for N=50000 (<=256)

    // ---- dst-CSR build ----
    hipMemsetAsync(cnt, 0, (size_t)2 * N * sizeof(int), stream);
    k_count<<<(E + 255) / 256, 256, 0, stream>>>(ei, cnt, E, E);
    k_scanA<<<nbScan, 256, 0, stream>>>(cnt, offs, bsum, N);
    k_scanB<<<1, 256, 0, stream>>>(bsum, nbScan);
    k_scanC<<<nbScan, 256, 0, stream>>>(offs, bsum, N);
    k_fillD<<<(E + 255) / 256, 256, 0, stream>>>(ei, offs, cursor, slotOf, E);

    if (fact) {
        // ---- src-CSR (edge permutation sorted by src) ----
        hipMemsetAsync(cntS, 0, (size_t)2 * N * sizeof(int), stream);
        k_count<<<(E + 255) / 256, 256, 0, stream>>>(ei, cntS, E, 0);
        k_scanA<<<nbScan, 256, 0, stream>>>(cntS, offsS, bsumS, N);
        k_scanB<<<1, 256, 0, stream>>>(bsumS, nbScan);
        k_scanC<<<nbScan, 256, 0, stream>>>(offsS, bsumS, N);
        k_fillS<<<(E + 255) / 256, 256, 0, stream>>>(ei, offsS, cursorS, permS, E);
    }

    for (int l = 0; l < 4; l++) {
        hipMemsetAsync(stats, 0, 64 * sizeof(float), stream);
        const float* hcur = (l == 0) ? x : hbuf;
        if (fact) {
            k_u<<<(N * 16 + 255) / 256, 256, 0, stream>>>(hcur, w2, U, N);
            k_hb<<<(N * 16 + 255) / 256, 256, 0, stream>>>(hcur, b2, U, N);
            k_conv2<<<(E + 255) / 256, 256, 0, stream>>>(ei, ea, w1, b1, U, permS, slotOf, msg, E);
        } else {
            k_conv<<<(E/2 + 255) / 256, 256, 0, stream>>>(hcur, ei, ea, w1, b1, w2, b2, slotOf, msg, E);
        }
        k_node<<<(N*16 + 255) / 256, 256, 0, stream>>>(hcur, msg, offs, cnt, root[l], cb[l], h2, stats, N);
        k_bn<<<(N*16 + 255) / 256, 256, 0, stream>>>(h2, stats, g[l], be[l], hbuf, N, 1.0f / N);
    }
    k_z<<<(N*16 + 255) / 256, 256, 0, stream>>>(hbuf, mu_w, mu_b, lv_w, lv_b, eps, zbuf, N);
    k_dec<<<(E + 63) / 64, 128, 0, stream>>>(zbuf, ei,
        dw[0], db[0], dw[1], db[1], dw[2], db[2], dw[3], db[3], dw[4], db[4], out, E);
}